// Round 6
// baseline (165.153 us; speedup 1.0000x reference)
//
#include <hip/hip_runtime.h>
#include <hip/hip_bf16.h>

#define B_ 8
#define T_ 2048
#define C_ 1024
#define H_ 64

typedef __bf16 bf16x8 __attribute__((ext_vector_type(8)));
typedef float f32x4 __attribute__((ext_vector_type(4)));

typedef __attribute__((address_space(3))) unsigned int lds_u32;
typedef const __attribute__((address_space(1))) unsigned int glb_u32;
__device__ __forceinline__ void gl_lds16(const void* gp, void* lp) {
  __builtin_amdgcn_global_load_lds((glb_u32*)gp, (lds_u32*)lp, 16, 0, 0);
}

// ---------------- Kernel 0: weight transpose + bf16 cast ----------------
// Wt[m][h][c] = W_m[c][h] (* 1/32 for m==0, folding in scale = C^-0.5)
__global__ __launch_bounds__(256) void prep_w_k(const float* __restrict__ Wq,
                                                const float* __restrict__ Wk,
                                                const float* __restrict__ Wv,
                                                __bf16* __restrict__ Wt) {
  int idx = blockIdx.x * 256 + threadIdx.x;  // 49152 total (3*64*256)
  int m = idx >> 14;
  int rem = idx & 16383;
  int h = rem >> 8;
  int c4 = (rem & 255) << 2;
  const float* W = (m == 0) ? Wq : ((m == 1) ? Wk : Wv);
  float sc = (m == 0) ? 0.03125f : 1.0f;
  __bf16* dst = Wt + ((size_t)(m * H_ + h)) * C_ + c4;
#pragma unroll
  for (int i = 0; i < 4; ++i) dst[i] = (__bf16)(W[(size_t)(c4 + i) * H_ + h] * sc);
}

// ---------------- Kernel 1: QKV projection, 4-deep gl_lds ring ----------------
// grid 512 (32 rows each), 256 thr = 4 waves; wave wc covers 32 rows x 48 cols.
// Ring of 4 buffers x 16 KB: A = 32x128B (f32, XOR-swz 16B chunks), B = 4 planes x 192 x 16B.
__global__ __launch_bounds__(256) void qkv_k(const float* __restrict__ x,
                                             const __bf16* __restrict__ Wt,
                                             __bf16* __restrict__ q,
                                             __bf16* __restrict__ kk,
                                             __bf16* __restrict__ vt) {
  __shared__ __align__(16) char smem[65536];
  const int tid = threadIdx.x;
  const int lane = tid & 63;
  const int wc = tid >> 6;     // wave = col-quarter
  const int l15 = lane & 15;
  const int g = lane >> 4;
  const int row0 = blockIdx.x * 32;

  // staging addresses
  const int srow = tid >> 3;                   // 0..31
  const int sch = (tid & 7) ^ (srow & 7);      // source pre-swizzle
  const char* agsrc = (const char*)(x + (size_t)(row0 + srow) * C_) + sch * 16;
  const int adst = tid * 16;
  const char* bgs[3];
#pragma unroll
  for (int i = 0; i < 3; ++i) {
    int c = i * 256 + tid;
    int bg = c / 192;
    int bcol = c - bg * 192;
    bgs[i] = (const char*)Wt + bcol * 2048 + bg * 16;
  }
  const int bdst = 4096 + tid * 16;

  f32x4 acc[2][3];
#pragma unroll
  for (int rt = 0; rt < 2; ++rt)
#pragma unroll
    for (int ctl = 0; ctl < 3; ++ctl) acc[rt][ctl] = (f32x4)0.0f;

  auto stage = [&](int t, int bufo) {
    const size_t ao = (size_t)t << 7;   // 128 B per K-step (A)
    const size_t bo = (size_t)t << 6;   // 64 B per K-step (B)
    gl_lds16(agsrc + ao, smem + bufo + adst);
    gl_lds16(bgs[0] + bo, smem + bufo + bdst);
    gl_lds16(bgs[1] + bo, smem + bufo + 4096 + bdst);
    gl_lds16(bgs[2] + bo, smem + bufo + 8192 + bdst);
  };

  // prologue: stage t=0,1,2
  stage(0, 0);
  stage(1, 16384);
  stage(2, 32768);

  for (int t = 0; t < 32; ++t) {
    const int rem = 31 - t;
    if (rem >= 2) {
      asm volatile("s_waitcnt vmcnt(8)" ::: "memory");
    } else if (rem == 1) {
      asm volatile("s_waitcnt vmcnt(4)" ::: "memory");
    } else {
      asm volatile("s_waitcnt vmcnt(0)" ::: "memory");
    }
    __builtin_amdgcn_s_barrier();
    if (t + 3 < 32) stage(t + 3, ((t + 3) & 3) << 14);
    const int cur = (t & 3) << 14;
    // compute from cur
    bf16x8 af[2];
#pragma unroll
    for (int rt = 0; rt < 2; ++rt) {
      const int row = rt * 16 + l15;
      const char* ab = smem + cur + row * 128;
      f32x4 a0 = *(const f32x4*)(ab + ((((g << 1)) ^ (row & 7)) << 4));
      f32x4 a1 = *(const f32x4*)(ab + ((((g << 1) | 1) ^ (row & 7)) << 4));
#pragma unroll
      for (int j = 0; j < 4; ++j) {
        af[rt][j] = (__bf16)a0[j];
        af[rt][4 + j] = (__bf16)a1[j];
      }
    }
#pragma unroll
    for (int ctl = 0; ctl < 3; ++ctl) {
      const int col = wc * 48 + ctl * 16 + l15;
      bf16x8 bf = *(const bf16x8*)(smem + cur + 4096 + g * 3072 + col * 16);
      acc[0][ctl] = __builtin_amdgcn_mfma_f32_16x16x32_bf16(af[0], bf, acc[0][ctl], 0, 0, 0);
      acc[1][ctl] = __builtin_amdgcn_mfma_f32_16x16x32_bf16(af[1], bf, acc[1][ctl], 0, 0, 0);
    }
  }

  // epilogue: q/k direct, v via swizzled LDS transpose -> vt[b][h][t]
  // (vtile in smem[0,4096) = buf0 A-region; buf0 last read at t=28 — all waves
  //  passed barriers t=29..31, so it's free; t=31's vmcnt(0) drained all loads)
#pragma unroll
  for (int rt = 0; rt < 2; ++rt)
#pragma unroll
    for (int ctl = 0; ctl < 3; ++ctl) {
      const int cb = wc * 48 + ctl * 16;
      const int m = cb >> 6;
      const int drow = row0 + rt * 16 + g * 4;
      if (m == 0) {
#pragma unroll
        for (int r = 0; r < 4; ++r)
          q[(size_t)(drow + r) * H_ + (cb & 63) + l15] = (__bf16)acc[rt][ctl][r];
      } else if (m == 1) {
#pragma unroll
        for (int r = 0; r < 4; ++r)
          kk[(size_t)(drow + r) * H_ + (cb & 63) + l15] = (__bf16)acc[rt][ctl][r];
      } else {
        const int vh = (cb - 128) + l15;
        const int t0 = rt * 16 + g * 4;
        union { ushort4 u; __bf16 h[4]; } pk;
#pragma unroll
        for (int r = 0; r < 4; ++r) pk.h[r] = (__bf16)acc[rt][ctl][r];
        int off = ((vh * 32 + t0) * 2) ^ ((vh & 7) << 4);
        *(ushort4*)(smem + off) = pk.u;
      }
    }
  __syncthreads();
  {
    const int h = tid >> 2;
    const int t8 = (tid & 3) * 8;
    const int sw = (h & 7) << 4;
    unsigned long long u0 = *(const unsigned long long*)(smem + (((h * 32 + t8) * 2) ^ sw));
    unsigned long long u1 = *(const unsigned long long*)(smem + (((h * 32 + t8 + 4) * 2) ^ sw));
    const int bb = blockIdx.x >> 6;
    const int tglob = (blockIdx.x & 63) * 32 + t8;
    unsigned long long* dst =
        (unsigned long long*)(vt + ((size_t)bb * 64 + h) * T_ + tglob);
    dst[0] = u0;
    dst[1] = u1;
  }
}

// ---------------- Kernel 2: causal flash attention, split-KV, ring-3 LDS K/V ----------------
// grid = b(8) x qb(32) x piece(SPLIT); 4 waves x 16 q-rows; KVBLK=64
// LDS: ring3 x {K 8KB + V 8KB} = 48 KB + P 8 KB = 56 KB
template <int SPLIT>
__global__ __launch_bounds__(256) void attn_k(const __bf16* __restrict__ q,
                                              const __bf16* __restrict__ k,
                                              const __bf16* __restrict__ vt,
                                              float* __restrict__ Opart,
                                              float2* __restrict__ ml) {
  __shared__ __align__(16) char smem[57344];
  const int bid = blockIdx.x;
  const int p = bid % SPLIT;
  const int qb = (bid / SPLIT) & 31;
  const int b = bid / (SPLIT * 32);
  const int tid = threadIdx.x;
  const int lane = tid & 63;
  const int w = tid >> 6;
  const int l15 = lane & 15;
  const int g = lane >> 4;
  const size_t qkbase = (size_t)b * T_ * H_;
  const int qr0 = qb * 64 + w * 16;

  const __bf16* qp = q + qkbase + (size_t)(qr0 + l15) * H_ + g * 8;
  bf16x8 aq0 = *(const bf16x8*)qp;
  bf16x8 aq1 = *(const bf16x8*)(qp + 32);

  // staging: K tile 64x128B (row=kv, chunk=h/8), V tile 64x128B (row=h, chunk=t/8)
  const int r0c = tid >> 3, x0c = (tid & 7) ^ (r0c & 7);
  const int r1c = (tid + 256) >> 3, x1c = (tid & 7) ^ (r1c & 7);
  const __bf16* ks0 = k + qkbase + (size_t)r0c * H_ + x0c * 8;
  const __bf16* ks1 = k + qkbase + (size_t)r1c * H_ + x1c * 8;
  const __bf16* vbase = vt + (size_t)b * 64 * T_;
  const __bf16* vs0 = vbase + (size_t)r0c * T_ + x0c * 8;
  const __bf16* vs1 = vbase + (size_t)r1c * T_ + x1c * 8;
  const int d0 = tid * 16, d1 = 4096 + tid * 16;

  auto stage = [&](int kvb, int bufo) {
    gl_lds16(ks0 + (size_t)kvb * H_, smem + bufo + d0);
    gl_lds16(ks1 + (size_t)kvb * H_, smem + bufo + d1);
    gl_lds16(vs0 + kvb, smem + bufo + 8192 + d0);
    gl_lds16(vs1 + kvb, smem + bufo + 8192 + d1);
  };

  f32x4 accO[4];
#pragma unroll
  for (int i = 0; i < 4; ++i) accO[i] = (f32x4)0.0f;
  float mrow[4] = {-1e30f, -1e30f, -1e30f, -1e30f};
  float lsum[4] = {0.f, 0.f, 0.f, 0.f};
  char* pb = smem + 49152 + w * 2048;

  const int len = (qb + SPLIT) / SPLIT;  // ceil((qb+1)/SPLIT)
  const int kb0 = p * len;
  int kbend = kb0 + len;
  if (kbend > qb + 1) kbend = qb + 1;
  const int n = kbend - kb0;

  if (n > 0) {
    stage(kb0 * 64, 0);
    if (n > 1) stage((kb0 + 1) * 64, 16384);
    for (int i = 0; i < n; ++i) {
      if (i + 1 < n) {
        asm volatile("s_waitcnt vmcnt(4)" ::: "memory");
      } else {
        asm volatile("s_waitcnt vmcnt(0)" ::: "memory");
      }
      __builtin_amdgcn_s_barrier();
      if (i + 2 < n) stage((kb0 + i + 2) * 64, ((i + 2) % 3) * 16384);
      const int kb = kb0 + i;
      const int kvb = kb * 64;
      const char* kbuf = smem + (i % 3) * 16384;
      const char* vbuf = kbuf + 8192;
      // S = Q K^T (scale pre-folded into q)
      f32x4 s[4];
#pragma unroll
      for (int ct = 0; ct < 4; ++ct) {
        const int row = ct * 16 + l15;
        bf16x8 b0 = *(const bf16x8*)(kbuf + row * 128 + ((g ^ (row & 7)) << 4));
        bf16x8 b1 = *(const bf16x8*)(kbuf + row * 128 + (((g + 4) ^ (row & 7)) << 4));
        f32x4 z = (f32x4)0.0f;
        z = __builtin_amdgcn_mfma_f32_16x16x32_bf16(aq0, b0, z, 0, 0, 0);
        z = __builtin_amdgcn_mfma_f32_16x16x32_bf16(aq1, b1, z, 0, 0, 0);
        s[ct] = z;
      }
      if (kb == qb) {  // causal mask on diagonal block
#pragma unroll
        for (int ct = 0; ct < 4; ++ct)
#pragma unroll
          for (int r = 0; r < 4; ++r)
            if (kvb + ct * 16 + l15 > qr0 + g * 4 + r) s[ct][r] = -1e30f;
      }
      // wave-parallel online softmax
      float al[4];
#pragma unroll
      for (int r = 0; r < 4; ++r) {
        float v = fmaxf(fmaxf(s[0][r], s[1][r]), fmaxf(s[2][r], s[3][r]));
        v = fmaxf(v, __shfl_xor(v, 1, 64));
        v = fmaxf(v, __shfl_xor(v, 2, 64));
        v = fmaxf(v, __shfl_xor(v, 4, 64));
        v = fmaxf(v, __shfl_xor(v, 8, 64));
        float m2 = fmaxf(mrow[r], v);
        al[r] = __expf(mrow[r] - m2);
        mrow[r] = m2;
      }
#pragma unroll
      for (int ct = 0; ct < 4; ++ct)
#pragma unroll
        for (int r = 0; r < 4; ++r) s[ct][r] = __expf(s[ct][r] - mrow[r]);
#pragma unroll
      for (int r = 0; r < 4; ++r) {
        lsum[r] = lsum[r] * al[r] + (s[0][r] + s[1][r]) + (s[2][r] + s[3][r]);
#pragma unroll
        for (int hct = 0; hct < 4; ++hct) accO[hct][r] *= al[r];
      }
      // P -> per-wave LDS tile (swizzled), read back as A-fragments
#pragma unroll
      for (int ct = 0; ct < 4; ++ct)
#pragma unroll
        for (int r = 0; r < 4; ++r) {
          int qrow = g * 4 + r;
          int off = ((qrow * 64 + ct * 16 + l15) * 2) ^ ((qrow & 7) << 4);
          *(__bf16*)(pb + off) = (__bf16)s[ct][r];
        }
#pragma unroll
      for (int ks = 0; ks < 2; ++ks) {
        int off = ((l15 * 64 + ks * 32 + g * 8) * 2) ^ ((l15 & 7) << 4);
        bf16x8 pa = *(const bf16x8*)(pb + off);
#pragma unroll
        for (int hct = 0; hct < 4; ++hct) {
          const int h = hct * 16 + l15;
          const int chunk = ks * 4 + g;
          bf16x8 bv = *(const bf16x8*)(vbuf + h * 128 + ((chunk ^ (h & 7)) << 4));
          accO[hct] = __builtin_amdgcn_mfma_f32_16x16x32_bf16(pa, bv, accO[hct], 0, 0, 0);
        }
      }
    }
  }
  // reduce lsum across 16-lane group; write partials (unnormalized)
#pragma unroll
  for (int r = 0; r < 4; ++r) {
    float v = lsum[r];
    v += __shfl_xor(v, 1, 64);
    v += __shfl_xor(v, 2, 64);
    v += __shfl_xor(v, 4, 64);
    v += __shfl_xor(v, 8, 64);
    lsum[r] = v;
  }
  float* op = Opart + ((size_t)p * (B_ * T_) + (size_t)b * T_ + qr0) * H_;
#pragma unroll
  for (int hct = 0; hct < 4; ++hct)
#pragma unroll
    for (int r = 0; r < 4; ++r)
      op[(size_t)(g * 4 + r) * H_ + hct * 16 + l15] = accO[hct][r];
  if (l15 == 0) {
#pragma unroll
    for (int r = 0; r < 4; ++r)
      ml[(size_t)p * (B_ * T_) + (size_t)b * T_ + qr0 + g * 4 + r] =
          make_float2(mrow[r], lsum[r]);
  }
}

// ---------------- Kernel 3: combine split-KV partials ----------------
template <int SPLIT>
__global__ __launch_bounds__(256) void comb_k(const float* __restrict__ Opart,
                                              const float2* __restrict__ ml,
                                              float* __restrict__ out) {
  int gid = blockIdx.x * 256 + threadIdx.x;  // 262144 = 16384 rows x 16
  int row = gid >> 4;
  int h4 = (gid & 15) * 4;
  float m[SPLIT], l[SPLIT];
#pragma unroll
  for (int p = 0; p < SPLIT; ++p) {
    float2 t = ml[(size_t)p * (B_ * T_) + row];
    m[p] = t.x;
    l[p] = t.y;
  }
  float M = -1e30f;
#pragma unroll
  for (int p = 0; p < SPLIT; ++p) M = fmaxf(M, m[p]);
  float wp[SPLIT], wsum = 0.f;
#pragma unroll
  for (int p = 0; p < SPLIT; ++p) {
    wp[p] = __expf(m[p] - M);
    wsum += wp[p] * l[p];
  }
  float4 o = make_float4(0.f, 0.f, 0.f, 0.f);
#pragma unroll
  for (int p = 0; p < SPLIT; ++p) {
    float4 a = *(const float4*)(Opart + ((size_t)p * (B_ * T_) + row) * H_ + h4);
    o.x += wp[p] * a.x;
    o.y += wp[p] * a.y;
    o.z += wp[p] * a.z;
    o.w += wp[p] * a.w;
  }
  float inv = 1.0f / wsum;
  *(float4*)(out + (size_t)row * H_ + h4) =
      make_float4(o.x * inv, o.y * inv, o.z * inv, o.w * inv);
}

// ---------------- launcher ----------------
extern "C" void kernel_launch(void* const* d_in, const int* in_sizes, int n_in,
                              void* d_out, int out_size, void* d_ws, size_t ws_size,
                              hipStream_t stream) {
  const float* x  = (const float*)d_in[0];
  const float* Wq = (const float*)d_in[1];
  const float* Wk = (const float*)d_in[2];
  const float* Wv = (const float*)d_in[3];
  float* out = (float*)d_out;
  char* ws = (char*)d_ws;
  __bf16* Wt   = (__bf16*)ws;                  // 384 KiB
  __bf16* qb   = (__bf16*)(ws + 0x60000);      // 2 MiB
  __bf16* kb   = (__bf16*)(ws + 0x260000);     // 2 MiB
  __bf16* vtb  = (__bf16*)(ws + 0x460000);     // 2 MiB (vt[b][h][t])
  float*  Op   = (float*)(ws + 0x660000);      // 8 MiB (2 x 16384 x 64 f32)
  float2* mlb  = (float2*)(ws + 0xE60000);     // 256 KiB

  hipLaunchKernelGGL(prep_w_k, dim3(192), dim3(256), 0, stream, Wq, Wk, Wv, Wt);
  hipLaunchKernelGGL(qkv_k, dim3(512), dim3(256), 0, stream, x, Wt, qb, kb, vtb);
  hipLaunchKernelGGL(attn_k<2>, dim3(8 * 32 * 2), dim3(256), 0, stream, qb, kb, vtb, Op, mlb);
  hipLaunchKernelGGL(comb_k<2>, dim3(1024), dim3(256), 0, stream, Op, mlb, out);
}

// Round 7
// 147.842 us; speedup vs baseline: 1.1171x; 1.1171x over previous
//
#include <hip/hip_runtime.h>
#include <hip/hip_bf16.h>

#define B_ 8
#define T_ 2048
#define C_ 1024
#define H_ 64

typedef __bf16 bf16x8 __attribute__((ext_vector_type(8)));
typedef float f32x4 __attribute__((ext_vector_type(4)));

typedef __attribute__((address_space(3))) unsigned int lds_u32;
typedef const __attribute__((address_space(1))) unsigned int glb_u32;
__device__ __forceinline__ void gl_lds16(const void* gp, void* lp) {
  __builtin_amdgcn_global_load_lds((glb_u32*)gp, (lds_u32*)lp, 16, 0, 0);
}

// ---------------- Kernel 0: weight transpose + bf16 cast, STAGED layout ----------------
// Wt2[t][g][col][8] (bf16) = W_m[c][h] * sc,  c = t*32+g*8+j, col = m*64+h.
// This is the exact linear order qkv_k's B-staging consumes -> coalesced gl_lds.
__global__ __launch_bounds__(256) void prep_w_k(const float* __restrict__ Wq,
                                                const float* __restrict__ Wk,
                                                const float* __restrict__ Wv,
                                                __bf16* __restrict__ Wt2) {
  int idx = blockIdx.x * 256 + threadIdx.x;  // 49152 total (3*64*256)
  int m = idx >> 14;
  int rem = idx & 16383;
  int h = rem >> 8;
  int cb = (rem & 255) * 4;   // 4 consecutive c, within one 8-block
  const float* W = (m == 0) ? Wq : ((m == 1) ? Wk : Wv);
  float sc = (m == 0) ? 0.03125f : 1.0f;
  const int col = m * 64 + h;
  const int t = cb >> 5;
  const int g = (cb >> 3) & 3;
  const int j = cb & 7;       // 0 or 4
  __bf16* dst = Wt2 + (((size_t)(t * 4 + g) * 192 + col) * 8 + j);
#pragma unroll
  for (int i = 0; i < 4; ++i) dst[i] = (__bf16)(W[(size_t)(cb + i) * H_ + h] * sc);
}

// ---------------- Kernel 1: QKV projection, 4-deep gl_lds ring, coalesced B ----------------
// grid 512 (32 rows each), 256 thr = 4 waves; wave wc covers 32 rows x 48 cols.
// Ring of 4 buffers x 16 KB: A = 32x128B (f32, XOR-swz 16B chunks), B = [g][col][16B].
__global__ __launch_bounds__(256) void qkv_k(const float* __restrict__ x,
                                             const __bf16* __restrict__ Wt2,
                                             __bf16* __restrict__ q,
                                             __bf16* __restrict__ kk,
                                             __bf16* __restrict__ vt) {
  __shared__ __align__(16) char smem[65536];
  const int tid = threadIdx.x;
  const int lane = tid & 63;
  const int wc = tid >> 6;     // wave = col-quarter
  const int l15 = lane & 15;
  const int g = lane >> 4;
  const int row0 = blockIdx.x * 32;

  // staging addresses
  const int srow = tid >> 3;                   // 0..31
  const int sch = (tid & 7) ^ (srow & 7);      // source pre-swizzle (A)
  const char* agsrc = (const char*)(x + (size_t)(row0 + srow) * C_) + sch * 16;
  const int adst = tid * 16;
  const char* b2src = (const char*)Wt2 + tid * 16;   // + t*12288 + i*4096

  f32x4 acc[2][3];
#pragma unroll
  for (int rt = 0; rt < 2; ++rt)
#pragma unroll
    for (int ctl = 0; ctl < 3; ++ctl) acc[rt][ctl] = (f32x4)0.0f;

  auto stage = [&](int t, int bufo) {
    gl_lds16(agsrc + ((size_t)t << 7), smem + bufo + adst);
    const char* bs = b2src + (size_t)t * 12288;
    gl_lds16(bs, smem + bufo + 4096 + tid * 16);
    gl_lds16(bs + 4096, smem + bufo + 8192 + tid * 16);
    gl_lds16(bs + 8192, smem + bufo + 12288 + tid * 16);
  };

  // prologue: stage t=0,1,2
  stage(0, 0);
  stage(1, 16384);
  stage(2, 32768);

  for (int t = 0; t < 32; ++t) {
    const int rem = 31 - t;
    if (rem >= 2) {
      asm volatile("s_waitcnt vmcnt(8)" ::: "memory");
    } else if (rem == 1) {
      asm volatile("s_waitcnt vmcnt(4)" ::: "memory");
    } else {
      asm volatile("s_waitcnt vmcnt(0)" ::: "memory");
    }
    __builtin_amdgcn_s_barrier();
    if (t + 3 < 32) stage(t + 3, ((t + 3) & 3) << 14);
    const int cur = (t & 3) << 14;
    // compute from cur
    bf16x8 af[2];
#pragma unroll
    for (int rt = 0; rt < 2; ++rt) {
      const int row = rt * 16 + l15;
      const char* ab = smem + cur + row * 128;
      f32x4 a0 = *(const f32x4*)(ab + ((((g << 1)) ^ (row & 7)) << 4));
      f32x4 a1 = *(const f32x4*)(ab + ((((g << 1) | 1) ^ (row & 7)) << 4));
#pragma unroll
      for (int j = 0; j < 4; ++j) {
        af[rt][j] = (__bf16)a0[j];
        af[rt][4 + j] = (__bf16)a1[j];
      }
    }
#pragma unroll
    for (int ctl = 0; ctl < 3; ++ctl) {
      const int col = wc * 48 + ctl * 16 + l15;
      bf16x8 bf = *(const bf16x8*)(smem + cur + 4096 + g * 3072 + col * 16);
      acc[0][ctl] = __builtin_amdgcn_mfma_f32_16x16x32_bf16(af[0], bf, acc[0][ctl], 0, 0, 0);
      acc[1][ctl] = __builtin_amdgcn_mfma_f32_16x16x32_bf16(af[1], bf, acc[1][ctl], 0, 0, 0);
    }
  }

  // epilogue: q/k direct, v via swizzled LDS transpose -> vt[b][h][t]
  // (vtile in smem[0,4096) = buf0 A-region; buf0 last read at t=28; all waves
  //  passed barriers t=29..31 and t=31 drained vmcnt(0) -> free)
#pragma unroll
  for (int rt = 0; rt < 2; ++rt)
#pragma unroll
    for (int ctl = 0; ctl < 3; ++ctl) {
      const int cb = wc * 48 + ctl * 16;
      const int m = cb >> 6;
      const int drow = row0 + rt * 16 + g * 4;
      if (m == 0) {
#pragma unroll
        for (int r = 0; r < 4; ++r)
          q[(size_t)(drow + r) * H_ + (cb & 63) + l15] = (__bf16)acc[rt][ctl][r];
      } else if (m == 1) {
#pragma unroll
        for (int r = 0; r < 4; ++r)
          kk[(size_t)(drow + r) * H_ + (cb & 63) + l15] = (__bf16)acc[rt][ctl][r];
      } else {
        const int vh = (cb - 128) + l15;
        const int t0 = rt * 16 + g * 4;
        union { ushort4 u; __bf16 h[4]; } pk;
#pragma unroll
        for (int r = 0; r < 4; ++r) pk.h[r] = (__bf16)acc[rt][ctl][r];
        int off = ((vh * 32 + t0) * 2) ^ ((vh & 7) << 4);
        *(ushort4*)(smem + off) = pk.u;
      }
    }
  __syncthreads();
  {
    const int h = tid >> 2;
    const int t8 = (tid & 3) * 8;
    const int sw = (h & 7) << 4;
    unsigned long long u0 = *(const unsigned long long*)(smem + (((h * 32 + t8) * 2) ^ sw));
    unsigned long long u1 = *(const unsigned long long*)(smem + (((h * 32 + t8 + 4) * 2) ^ sw));
    const int bb = blockIdx.x >> 6;
    const int tglob = (blockIdx.x & 63) * 32 + t8;
    unsigned long long* dst =
        (unsigned long long*)(vt + ((size_t)bb * 64 + h) * T_ + tglob);
    dst[0] = u0;
    dst[1] = u1;
  }
}

// ---------------- Kernel 2: causal flash attention, split-KV, ring-4 LDS K/V ----------------
// grid = b(8) x qb(32) x piece(SPLIT); 4 waves x 16 q-rows; KVBLK=64
// LDS: ring4 x {K 8KB + V 8KB} = 64 KB + P 8 KB = 72 KB (+pad) -> 2 blocks/CU
template <int SPLIT>
__global__ __launch_bounds__(256) void attn_k(const __bf16* __restrict__ q,
                                              const __bf16* __restrict__ k,
                                              const __bf16* __restrict__ vt,
                                              float* __restrict__ Opart,
                                              float2* __restrict__ ml) {
  __shared__ __align__(16) char smem[73728];
  const int bid = blockIdx.x;
  const int p = bid % SPLIT;
  const int qb = (bid / SPLIT) & 31;
  const int b = bid / (SPLIT * 32);
  const int tid = threadIdx.x;
  const int lane = tid & 63;
  const int w = tid >> 6;
  const int l15 = lane & 15;
  const int g = lane >> 4;
  const size_t qkbase = (size_t)b * T_ * H_;
  const int qr0 = qb * 64 + w * 16;

  const __bf16* qp = q + qkbase + (size_t)(qr0 + l15) * H_ + g * 8;
  bf16x8 aq0 = *(const bf16x8*)qp;
  bf16x8 aq1 = *(const bf16x8*)(qp + 32);
  // drain Q loads so in-loop vmcnt counting is exact
  asm volatile("s_waitcnt vmcnt(0)" ::: "memory");

  // staging: K tile 64x128B (row=kv, chunk=h/8), V tile 64x128B (row=h, chunk=t/8)
  const int r0c = tid >> 3, x0c = (tid & 7) ^ (r0c & 7);
  const int r1c = (tid + 256) >> 3, x1c = (tid & 7) ^ (r1c & 7);
  const __bf16* ks0 = k + qkbase + (size_t)r0c * H_ + x0c * 8;
  const __bf16* ks1 = k + qkbase + (size_t)r1c * H_ + x1c * 8;
  const __bf16* vbase = vt + (size_t)b * 64 * T_;
  const __bf16* vs0 = vbase + (size_t)r0c * T_ + x0c * 8;
  const __bf16* vs1 = vbase + (size_t)r1c * T_ + x1c * 8;
  const int d0 = tid * 16, d1 = 4096 + tid * 16;

  auto stage = [&](int kvb, int bufo) {
    gl_lds16(ks0 + (size_t)kvb * H_, smem + bufo + d0);
    gl_lds16(ks1 + (size_t)kvb * H_, smem + bufo + d1);
    gl_lds16(vs0 + kvb, smem + bufo + 8192 + d0);
    gl_lds16(vs1 + kvb, smem + bufo + 8192 + d1);
  };

  f32x4 accO[4];
#pragma unroll
  for (int i = 0; i < 4; ++i) accO[i] = (f32x4)0.0f;
  float mrow[4] = {-1e30f, -1e30f, -1e30f, -1e30f};
  float lsum[4] = {0.f, 0.f, 0.f, 0.f};
  char* pb = smem + 65536 + w * 2048;

  const int len = (qb + SPLIT) / SPLIT;  // ceil((qb+1)/SPLIT)
  const int kb0 = p * len;
  int kbend = kb0 + len;
  if (kbend > qb + 1) kbend = qb + 1;
  const int n = kbend - kb0;

  if (n > 0) {
    stage(kb0 * 64, 0);
    if (n > 1) stage((kb0 + 1) * 64, 16384);
    if (n > 2) stage((kb0 + 2) * 64, 32768);
    for (int i = 0; i < n; ++i) {
      const int remn = n - 1 - i;
      if (remn >= 2) {
        asm volatile("s_waitcnt vmcnt(8)" ::: "memory");
      } else if (remn == 1) {
        asm volatile("s_waitcnt vmcnt(4)" ::: "memory");
      } else {
        asm volatile("s_waitcnt vmcnt(0)" ::: "memory");
      }
      __builtin_amdgcn_s_barrier();
      if (i + 3 < n) stage((kb0 + i + 3) * 64, ((i + 3) & 3) << 14);
      const int kb = kb0 + i;
      const int kvb = kb * 64;
      const char* kbuf = smem + ((i & 3) << 14);
      const char* vbuf = kbuf + 8192;
      // S = Q K^T (scale pre-folded into q)
      f32x4 s[4];
#pragma unroll
      for (int ct = 0; ct < 4; ++ct) {
        const int row = ct * 16 + l15;
        bf16x8 b0 = *(const bf16x8*)(kbuf + row * 128 + ((g ^ (row & 7)) << 4));
        bf16x8 b1 = *(const bf16x8*)(kbuf + row * 128 + (((g + 4) ^ (row & 7)) << 4));
        f32x4 z = (f32x4)0.0f;
        z = __builtin_amdgcn_mfma_f32_16x16x32_bf16(aq0, b0, z, 0, 0, 0);
        z = __builtin_amdgcn_mfma_f32_16x16x32_bf16(aq1, b1, z, 0, 0, 0);
        s[ct] = z;
      }
      if (kb == qb) {  // causal mask on diagonal block
#pragma unroll
        for (int ct = 0; ct < 4; ++ct)
#pragma unroll
          for (int r = 0; r < 4; ++r)
            if (kvb + ct * 16 + l15 > qr0 + g * 4 + r) s[ct][r] = -1e30f;
      }
      // wave-parallel online softmax
      float al[4];
#pragma unroll
      for (int r = 0; r < 4; ++r) {
        float v = fmaxf(fmaxf(s[0][r], s[1][r]), fmaxf(s[2][r], s[3][r]));
        v = fmaxf(v, __shfl_xor(v, 1, 64));
        v = fmaxf(v, __shfl_xor(v, 2, 64));
        v = fmaxf(v, __shfl_xor(v, 4, 64));
        v = fmaxf(v, __shfl_xor(v, 8, 64));
        float m2 = fmaxf(mrow[r], v);
        al[r] = __expf(mrow[r] - m2);
        mrow[r] = m2;
      }
#pragma unroll
      for (int ct = 0; ct < 4; ++ct)
#pragma unroll
        for (int r = 0; r < 4; ++r) s[ct][r] = __expf(s[ct][r] - mrow[r]);
#pragma unroll
      for (int r = 0; r < 4; ++r) {
        lsum[r] = lsum[r] * al[r] + (s[0][r] + s[1][r]) + (s[2][r] + s[3][r]);
#pragma unroll
        for (int hct = 0; hct < 4; ++hct) accO[hct][r] *= al[r];
      }
      // P -> per-wave LDS tile (swizzled), read back as A-fragments
#pragma unroll
      for (int ct = 0; ct < 4; ++ct)
#pragma unroll
        for (int r = 0; r < 4; ++r) {
          int qrow = g * 4 + r;
          int off = ((qrow * 64 + ct * 16 + l15) * 2) ^ ((qrow & 7) << 4);
          *(__bf16*)(pb + off) = (__bf16)s[ct][r];
        }
#pragma unroll
      for (int ks = 0; ks < 2; ++ks) {
        int off = ((l15 * 64 + ks * 32 + g * 8) * 2) ^ ((l15 & 7) << 4);
        bf16x8 pa = *(const bf16x8*)(pb + off);
#pragma unroll
        for (int hct = 0; hct < 4; ++hct) {
          const int h = hct * 16 + l15;
          const int chunk = ks * 4 + g;
          bf16x8 bv = *(const bf16x8*)(vbuf + h * 128 + ((chunk ^ (h & 7)) << 4));
          accO[hct] = __builtin_amdgcn_mfma_f32_16x16x32_bf16(pa, bv, accO[hct], 0, 0, 0);
        }
      }
    }
  }
  // reduce lsum across 16-lane group; write partials (unnormalized)
#pragma unroll
  for (int r = 0; r < 4; ++r) {
    float v = lsum[r];
    v += __shfl_xor(v, 1, 64);
    v += __shfl_xor(v, 2, 64);
    v += __shfl_xor(v, 4, 64);
    v += __shfl_xor(v, 8, 64);
    lsum[r] = v;
  }
  float* op = Opart + ((size_t)p * (B_ * T_) + (size_t)b * T_ + qr0) * H_;
#pragma unroll
  for (int hct = 0; hct < 4; ++hct)
#pragma unroll
    for (int r = 0; r < 4; ++r)
      op[(size_t)(g * 4 + r) * H_ + hct * 16 + l15] = accO[hct][r];
  if (l15 == 0) {
#pragma unroll
    for (int r = 0; r < 4; ++r)
      ml[(size_t)p * (B_ * T_) + (size_t)b * T_ + qr0 + g * 4 + r] =
          make_float2(mrow[r], lsum[r]);
  }
}

// ---------------- Kernel 3: combine split-KV partials ----------------
template <int SPLIT>
__global__ __launch_bounds__(256) void comb_k(const float* __restrict__ Opart,
                                              const float2* __restrict__ ml,
                                              float* __restrict__ out) {
  int gid = blockIdx.x * 256 + threadIdx.x;  // 262144 = 16384 rows x 16
  int row = gid >> 4;
  int h4 = (gid & 15) * 4;
  float m[SPLIT], l[SPLIT];
#pragma unroll
  for (int p = 0; p < SPLIT; ++p) {
    float2 t = ml[(size_t)p * (B_ * T_) + row];
    m[p] = t.x;
    l[p] = t.y;
  }
  float M = -1e30f;
#pragma unroll
  for (int p = 0; p < SPLIT; ++p) M = fmaxf(M, m[p]);
  float wp[SPLIT], wsum = 0.f;
#pragma unroll
  for (int p = 0; p < SPLIT; ++p) {
    wp[p] = __expf(m[p] - M);
    wsum += wp[p] * l[p];
  }
  float4 o = make_float4(0.f, 0.f, 0.f, 0.f);
#pragma unroll
  for (int p = 0; p < SPLIT; ++p) {
    float4 a = *(const float4*)(Opart + ((size_t)p * (B_ * T_) + row) * H_ + h4);
    o.x += wp[p] * a.x;
    o.y += wp[p] * a.y;
    o.z += wp[p] * a.z;
    o.w += wp[p] * a.w;
  }
  float inv = 1.0f / wsum;
  *(float4*)(out + (size_t)row * H_ + h4) =
      make_float4(o.x * inv, o.y * inv, o.z * inv, o.w * inv);
}

// ---------------- launcher ----------------
extern "C" void kernel_launch(void* const* d_in, const int* in_sizes, int n_in,
                              void* d_out, int out_size, void* d_ws, size_t ws_size,
                              hipStream_t stream) {
  const float* x  = (const float*)d_in[0];
  const float* Wq = (const float*)d_in[1];
  const float* Wk = (const float*)d_in[2];
  const float* Wv = (const float*)d_in[3];
  float* out = (float*)d_out;
  char* ws = (char*)d_ws;
  __bf16* Wt2  = (__bf16*)ws;                  // 384 KiB (staged layout)
  __bf16* qb   = (__bf16*)(ws + 0x60000);      // 2 MiB
  __bf16* kb   = (__bf16*)(ws + 0x260000);     // 2 MiB
  __bf16* vtb  = (__bf16*)(ws + 0x460000);     // 2 MiB (vt[b][h][t])
  float*  Op   = (float*)(ws + 0x660000);      // 8 MiB (2 x 16384 x 64 f32)
  float2* mlb  = (float2*)(ws + 0xE60000);     // 256 KiB

  hipLaunchKernelGGL(prep_w_k, dim3(192), dim3(256), 0, stream, Wq, Wk, Wv, Wt2);
  hipLaunchKernelGGL(qkv_k, dim3(512), dim3(256), 0, stream, x, Wt2, qb, kb, vtb);
  hipLaunchKernelGGL(attn_k<2>, dim3(8 * 32 * 2), dim3(256), 0, stream, qb, kb, vtb, Op, mlb);
  hipLaunchKernelGGL(comb_k<2>, dim3(1024), dim3(256), 0, stream, Op, mlb, out);
}

// Round 8
// 141.480 us; speedup vs baseline: 1.1673x; 1.0450x over previous
//
#include <hip/hip_runtime.h>
#include <hip/hip_bf16.h>

#define B_ 8
#define T_ 2048
#define C_ 1024
#define H_ 64

typedef __bf16 bf16x8 __attribute__((ext_vector_type(8)));
typedef float f32x4 __attribute__((ext_vector_type(4)));

typedef __attribute__((address_space(3))) unsigned int lds_u32;
typedef const __attribute__((address_space(1))) unsigned int glb_u32;
__device__ __forceinline__ void gl_lds16(const void* gp, void* lp) {
  __builtin_amdgcn_global_load_lds((glb_u32*)gp, (lds_u32*)lp, 16, 0, 0);
}

// ---------------- Kernel 0: weight transpose + bf16 cast, STAGED layout ----------------
// Wt2[kb][g][col][8] (bf16) = W_m[c][h] * sc,  c = kb*32+g*8+j, col = m*64+h.
__global__ __launch_bounds__(256) void prep_w_k(const float* __restrict__ Wq,
                                                const float* __restrict__ Wk,
                                                const float* __restrict__ Wv,
                                                __bf16* __restrict__ Wt2) {
  int idx = blockIdx.x * 256 + threadIdx.x;  // 49152 total (3*64*256)
  int m = idx >> 14;
  int rem = idx & 16383;
  int h = rem >> 8;
  int cb = (rem & 255) * 4;   // 4 consecutive c, within one 8-block
  const float* W = (m == 0) ? Wq : ((m == 1) ? Wk : Wv);
  float sc = (m == 0) ? 0.03125f : 1.0f;
  const int col = m * 64 + h;
  const int t = cb >> 5;
  const int g = (cb >> 3) & 3;
  const int j = cb & 7;       // 0 or 4
  __bf16* dst = Wt2 + (((size_t)(t * 4 + g) * 192 + col) * 8 + j);
#pragma unroll
  for (int i = 0; i < 4; ++i) dst[i] = (__bf16)(W[(size_t)(cb + i) * H_ + h] * sc);
}

// ---------------- Kernel 1: QKV projection, 64-row blocks, BK=64, ring-3 ----------------
// grid 256 x 512 thr (8 waves): wave (wr=w>>2, wc=w&3) -> 32 rows x 48 cols.
// Buffer (40 KB): A = 2 x [64 rows][128B] (XOR-swz 16B chunks) = 16 KB;
//                 B = 2 x [4 g][192 col][16B] = 24 KB.  Ring-3 = 120 KB LDS.
__global__ __launch_bounds__(512) void qkv_k(const float* __restrict__ x,
                                             const __bf16* __restrict__ Wt2,
                                             __bf16* __restrict__ q,
                                             __bf16* __restrict__ kk,
                                             __bf16* __restrict__ vt) {
  __shared__ __align__(16) char smem[122880];
  const int tid = threadIdx.x;
  const int lane = tid & 63;
  const int w = tid >> 6;      // 0..7
  const int wr = w >> 2;       // row half
  const int wc = w & 3;        // col quarter
  const int l15 = lane & 15;
  const int g = lane >> 4;
  const int row0 = blockIdx.x * 64;

  // staging addresses (per thread: 2 A-chunks + 3 B-chunks = 5 gl_lds/step)
  const int srow = tid >> 3;                   // 0..63
  const int sch = (tid & 7) ^ (srow & 7);      // source pre-swizzle (A)
  const char* agsrc = (const char*)x + ((size_t)(row0 + srow) * C_ + 0) * 4 + sch * 16;
  const int adst = tid * 16;
  const char* b2src = (const char*)Wt2 + tid * 16;
  const int bdst = 16384 + tid * 16;

  f32x4 acc[2][3];
#pragma unroll
  for (int rt = 0; rt < 2; ++rt)
#pragma unroll
    for (int ctl = 0; ctl < 3; ++ctl) acc[rt][ctl] = (f32x4)0.0f;

  auto stage = [&](int s, int bufo) {
    const char* as = agsrc + (size_t)s * 256;
    gl_lds16(as, smem + bufo + adst);
    gl_lds16(as + 128, smem + bufo + 8192 + adst);
    const char* bs = b2src + (size_t)s * 24576;
    gl_lds16(bs, smem + bufo + bdst);
    gl_lds16(bs + 8192, smem + bufo + 8192 + bdst);
    gl_lds16(bs + 16384, smem + bufo + 16384 + bdst);
  };

  // prologue: stage s=0,1
  stage(0, 0);
  stage(1, 40960);

  for (int s = 0; s < 16; ++s) {
    if (s < 15) {
      asm volatile("s_waitcnt vmcnt(5)" ::: "memory");
    } else {
      asm volatile("s_waitcnt vmcnt(0)" ::: "memory");
    }
    __builtin_amdgcn_s_barrier();
    if (s + 2 < 16) stage(s + 2, ((s + 2) % 3) * 40960);
    const int bufo = (s % 3) * 40960;
#pragma unroll
    for (int kbr = 0; kbr < 2; ++kbr) {
      const char* A = smem + bufo + kbr * 8192;
      const char* Bq = smem + bufo + 16384 + kbr * 12288 + g * 3072;
      bf16x8 af[2];
#pragma unroll
      for (int rt = 0; rt < 2; ++rt) {
        const int row = wr * 32 + rt * 16 + l15;
        const char* ab = A + row * 128;
        f32x4 a0 = *(const f32x4*)(ab + ((((g << 1)) ^ (row & 7)) << 4));
        f32x4 a1 = *(const f32x4*)(ab + ((((g << 1) | 1) ^ (row & 7)) << 4));
#pragma unroll
        for (int j = 0; j < 4; ++j) {
          af[rt][j] = (__bf16)a0[j];
          af[rt][4 + j] = (__bf16)a1[j];
        }
      }
#pragma unroll
      for (int ctl = 0; ctl < 3; ++ctl) {
        const int col = wc * 48 + ctl * 16 + l15;
        bf16x8 bf = *(const bf16x8*)(Bq + col * 16);
        acc[0][ctl] = __builtin_amdgcn_mfma_f32_16x16x32_bf16(af[0], bf, acc[0][ctl], 0, 0, 0);
        acc[1][ctl] = __builtin_amdgcn_mfma_f32_16x16x32_bf16(af[1], bf, acc[1][ctl], 0, 0, 0);
      }
    }
  }

  __syncthreads();  // compute(15) read buf0; V-tile below reuses smem[0,8192)

  // epilogue: q/k direct, v via swizzled LDS transpose -> vt[b][h][t]
#pragma unroll
  for (int rt = 0; rt < 2; ++rt)
#pragma unroll
    for (int ctl = 0; ctl < 3; ++ctl) {
      const int cb = wc * 48 + ctl * 16;
      const int m = cb >> 6;
      const int drow = row0 + wr * 32 + rt * 16 + g * 4;
      if (m == 0) {
#pragma unroll
        for (int r = 0; r < 4; ++r)
          q[(size_t)(drow + r) * H_ + (cb & 63) + l15] = (__bf16)acc[rt][ctl][r];
      } else if (m == 1) {
#pragma unroll
        for (int r = 0; r < 4; ++r)
          kk[(size_t)(drow + r) * H_ + (cb & 63) + l15] = (__bf16)acc[rt][ctl][r];
      } else {
        const int vh = (cb - 128) + l15;
        const int tl = wr * 32 + rt * 16 + g * 4;   // t-local 0..63
        union { ushort4 u; __bf16 h[4]; } pk;
#pragma unroll
        for (int r = 0; r < 4; ++r) pk.h[r] = (__bf16)acc[rt][ctl][r];
        int off = ((vh * 64 + tl) * 2) ^ ((vh & 7) << 4);
        *(ushort4*)(smem + off) = pk.u;
      }
    }
  __syncthreads();
  {
    const int h = tid >> 3;          // 0..63
    const int t8 = (tid & 7) * 8;    // 0..56
    const int sw = (h & 7) << 4;
    union { uint4 u; char c[16]; } v;
    v.u = *(const uint4*)(smem + (((h * 64 + t8) * 2) ^ sw));
    const int bb = blockIdx.x >> 5;
    const int tglob = (blockIdx.x & 31) * 64 + t8;
    *(uint4*)(vt + ((size_t)bb * 64 + h) * T_ + tglob) = v.u;
  }
}

// ---------------- Kernel 2: causal flash attention, split-KV, ring-4 LDS K/V ----------------
// grid = b(8) x qb(32) x piece(SPLIT); 4 waves x 16 q-rows; KVBLK=64
// LDS: ring4 x {K 8KB + V 8KB} = 64 KB + P 8 KB = 72 KB -> 2 blocks/CU
template <int SPLIT>
__global__ __launch_bounds__(256) void attn_k(const __bf16* __restrict__ q,
                                              const __bf16* __restrict__ k,
                                              const __bf16* __restrict__ vt,
                                              float* __restrict__ Opart,
                                              float2* __restrict__ ml) {
  __shared__ __align__(16) char smem[73728];
  const int bid = blockIdx.x;
  const int p = bid % SPLIT;
  const int qb = (bid / SPLIT) & 31;
  const int b = bid / (SPLIT * 32);
  const int tid = threadIdx.x;
  const int lane = tid & 63;
  const int w = tid >> 6;
  const int l15 = lane & 15;
  const int g = lane >> 4;
  const size_t qkbase = (size_t)b * T_ * H_;
  const int qr0 = qb * 64 + w * 16;

  const __bf16* qp = q + qkbase + (size_t)(qr0 + l15) * H_ + g * 8;
  bf16x8 aq0 = *(const bf16x8*)qp;
  bf16x8 aq1 = *(const bf16x8*)(qp + 32);
  // drain Q loads so in-loop vmcnt counting is exact
  asm volatile("s_waitcnt vmcnt(0)" ::: "memory");

  // staging: K tile 64x128B (row=kv, chunk=h/8), V tile 64x128B (row=h, chunk=t/8)
  const int r0c = tid >> 3, x0c = (tid & 7) ^ (r0c & 7);
  const int r1c = (tid + 256) >> 3, x1c = (tid & 7) ^ (r1c & 7);
  const __bf16* ks0 = k + qkbase + (size_t)r0c * H_ + x0c * 8;
  const __bf16* ks1 = k + qkbase + (size_t)r1c * H_ + x1c * 8;
  const __bf16* vbase = vt + (size_t)b * 64 * T_;
  const __bf16* vs0 = vbase + (size_t)r0c * T_ + x0c * 8;
  const __bf16* vs1 = vbase + (size_t)r1c * T_ + x1c * 8;
  const int d0 = tid * 16, d1 = 4096 + tid * 16;

  auto stage = [&](int kvb, int bufo) {
    gl_lds16(ks0 + (size_t)kvb * H_, smem + bufo + d0);
    gl_lds16(ks1 + (size_t)kvb * H_, smem + bufo + d1);
    gl_lds16(vs0 + kvb, smem + bufo + 8192 + d0);
    gl_lds16(vs1 + kvb, smem + bufo + 8192 + d1);
  };

  f32x4 accO[4];
#pragma unroll
  for (int i = 0; i < 4; ++i) accO[i] = (f32x4)0.0f;
  float mrow[4] = {-1e30f, -1e30f, -1e30f, -1e30f};
  float lsum[4] = {0.f, 0.f, 0.f, 0.f};
  char* pb = smem + 65536 + w * 2048;

  const int len = (qb + SPLIT) / SPLIT;  // ceil((qb+1)/SPLIT)
  const int kb0 = p * len;
  int kbend = kb0 + len;
  if (kbend > qb + 1) kbend = qb + 1;
  const int n = kbend - kb0;

  if (n > 0) {
    stage(kb0 * 64, 0);
    if (n > 1) stage((kb0 + 1) * 64, 16384);
    if (n > 2) stage((kb0 + 2) * 64, 32768);
    for (int i = 0; i < n; ++i) {
      const int remn = n - 1 - i;
      if (remn >= 2) {
        asm volatile("s_waitcnt vmcnt(8)" ::: "memory");
      } else if (remn == 1) {
        asm volatile("s_waitcnt vmcnt(4)" ::: "memory");
      } else {
        asm volatile("s_waitcnt vmcnt(0)" ::: "memory");
      }
      __builtin_amdgcn_s_barrier();
      if (i + 3 < n) stage((kb0 + i + 3) * 64, ((i + 3) & 3) << 14);
      const int kb = kb0 + i;
      const int kvb = kb * 64;
      const char* kbuf = smem + ((i & 3) << 14);
      const char* vbuf = kbuf + 8192;
      // S = Q K^T (scale pre-folded into q)
      f32x4 s[4];
#pragma unroll
      for (int ct = 0; ct < 4; ++ct) {
        const int row = ct * 16 + l15;
        bf16x8 b0 = *(const bf16x8*)(kbuf + row * 128 + ((g ^ (row & 7)) << 4));
        bf16x8 b1 = *(const bf16x8*)(kbuf + row * 128 + (((g + 4) ^ (row & 7)) << 4));
        f32x4 z = (f32x4)0.0f;
        z = __builtin_amdgcn_mfma_f32_16x16x32_bf16(aq0, b0, z, 0, 0, 0);
        z = __builtin_amdgcn_mfma_f32_16x16x32_bf16(aq1, b1, z, 0, 0, 0);
        s[ct] = z;
      }
      if (kb == qb) {  // causal mask on diagonal block
#pragma unroll
        for (int ct = 0; ct < 4; ++ct)
#pragma unroll
          for (int r = 0; r < 4; ++r)
            if (kvb + ct * 16 + l15 > qr0 + g * 4 + r) s[ct][r] = -1e30f;
      }
      // wave-parallel online softmax
      float al[4];
#pragma unroll
      for (int r = 0; r < 4; ++r) {
        float v = fmaxf(fmaxf(s[0][r], s[1][r]), fmaxf(s[2][r], s[3][r]));
        v = fmaxf(v, __shfl_xor(v, 1, 64));
        v = fmaxf(v, __shfl_xor(v, 2, 64));
        v = fmaxf(v, __shfl_xor(v, 4, 64));
        v = fmaxf(v, __shfl_xor(v, 8, 64));
        float m2 = fmaxf(mrow[r], v);
        al[r] = __expf(mrow[r] - m2);
        mrow[r] = m2;
      }
#pragma unroll
      for (int ct = 0; ct < 4; ++ct)
#pragma unroll
        for (int r = 0; r < 4; ++r) s[ct][r] = __expf(s[ct][r] - mrow[r]);
#pragma unroll
      for (int r = 0; r < 4; ++r) {
        lsum[r] = lsum[r] * al[r] + (s[0][r] + s[1][r]) + (s[2][r] + s[3][r]);
#pragma unroll
        for (int hct = 0; hct < 4; ++hct) accO[hct][r] *= al[r];
      }
      // P -> per-wave LDS tile (swizzled), read back as A-fragments
#pragma unroll
      for (int ct = 0; ct < 4; ++ct)
#pragma unroll
        for (int r = 0; r < 4; ++r) {
          int qrow = g * 4 + r;
          int off = ((qrow * 64 + ct * 16 + l15) * 2) ^ ((qrow & 7) << 4);
          *(__bf16*)(pb + off) = (__bf16)s[ct][r];
        }
#pragma unroll
      for (int ks = 0; ks < 2; ++ks) {
        int off = ((l15 * 64 + ks * 32 + g * 8) * 2) ^ ((l15 & 7) << 4);
        bf16x8 pa = *(const bf16x8*)(pb + off);
#pragma unroll
        for (int hct = 0; hct < 4; ++hct) {
          const int h = hct * 16 + l15;
          const int chunk = ks * 4 + g;
          bf16x8 bv = *(const bf16x8*)(vbuf + h * 128 + ((chunk ^ (h & 7)) << 4));
          accO[hct] = __builtin_amdgcn_mfma_f32_16x16x32_bf16(pa, bv, accO[hct], 0, 0, 0);
        }
      }
    }
  }
  // reduce lsum across 16-lane group; write partials (unnormalized)
#pragma unroll
  for (int r = 0; r < 4; ++r) {
    float v = lsum[r];
    v += __shfl_xor(v, 1, 64);
    v += __shfl_xor(v, 2, 64);
    v += __shfl_xor(v, 4, 64);
    v += __shfl_xor(v, 8, 64);
    lsum[r] = v;
  }
  float* op = Opart + ((size_t)p * (B_ * T_) + (size_t)b * T_ + qr0) * H_;
#pragma unroll
  for (int hct = 0; hct < 4; ++hct)
#pragma unroll
    for (int r = 0; r < 4; ++r)
      op[(size_t)(g * 4 + r) * H_ + hct * 16 + l15] = accO[hct][r];
  if (l15 == 0) {
#pragma unroll
    for (int r = 0; r < 4; ++r)
      ml[(size_t)p * (B_ * T_) + (size_t)b * T_ + qr0 + g * 4 + r] =
          make_float2(mrow[r], lsum[r]);
  }
}

// ---------------- Kernel 3: combine split-KV partials ----------------
template <int SPLIT>
__global__ __launch_bounds__(256) void comb_k(const float* __restrict__ Opart,
                                              const float2* __restrict__ ml,
                                              float* __restrict__ out) {
  int gid = blockIdx.x * 256 + threadIdx.x;  // 262144 = 16384 rows x 16
  int row = gid >> 4;
  int h4 = (gid & 15) * 4;
  float m[SPLIT], l[SPLIT];
#pragma unroll
  for (int p = 0; p < SPLIT; ++p) {
    float2 t = ml[(size_t)p * (B_ * T_) + row];
    m[p] = t.x;
    l[p] = t.y;
  }
  float M = -1e30f;
#pragma unroll
  for (int p = 0; p < SPLIT; ++p) M = fmaxf(M, m[p]);
  float wp[SPLIT], wsum = 0.f;
#pragma unroll
  for (int p = 0; p < SPLIT; ++p) {
    wp[p] = __expf(m[p] - M);
    wsum += wp[p] * l[p];
  }
  float4 o = make_float4(0.f, 0.f, 0.f, 0.f);
#pragma unroll
  for (int p = 0; p < SPLIT; ++p) {
    float4 a = *(const float4*)(Opart + ((size_t)p * (B_ * T_) + row) * H_ + h4);
    o.x += wp[p] * a.x;
    o.y += wp[p] * a.y;
    o.z += wp[p] * a.z;
    o.w += wp[p] * a.w;
  }
  float inv = 1.0f / wsum;
  *(float4*)(out + (size_t)row * H_ + h4) =
      make_float4(o.x * inv, o.y * inv, o.z * inv, o.w * inv);
}

// ---------------- launcher ----------------
extern "C" void kernel_launch(void* const* d_in, const int* in_sizes, int n_in,
                              void* d_out, int out_size, void* d_ws, size_t ws_size,
                              hipStream_t stream) {
  const float* x  = (const float*)d_in[0];
  const float* Wq = (const float*)d_in[1];
  const float* Wk = (const float*)d_in[2];
  const float* Wv = (const float*)d_in[3];
  float* out = (float*)d_out;
  char* ws = (char*)d_ws;
  __bf16* Wt2  = (__bf16*)ws;                  // 384 KiB (staged layout)
  __bf16* qb   = (__bf16*)(ws + 0x60000);      // 2 MiB
  __bf16* kb   = (__bf16*)(ws + 0x260000);     // 2 MiB
  __bf16* vtb  = (__bf16*)(ws + 0x460000);     // 2 MiB (vt[b][h][t])
  float*  Op   = (float*)(ws + 0x660000);      // 8 MiB (2 x 16384 x 64 f32)
  float2* mlb  = (float2*)(ws + 0xE60000);     // 256 KiB

  hipLaunchKernelGGL(prep_w_k, dim3(192), dim3(256), 0, stream, Wq, Wk, Wv, Wt2);
  hipLaunchKernelGGL(qkv_k, dim3(256), dim3(512), 0, stream, x, Wt2, qb, kb, vtb);
  hipLaunchKernelGGL(attn_k<2>, dim3(8 * 32 * 2), dim3(256), 0, stream, qb, kb, vtb, Op, mlb);
  hipLaunchKernelGGL(comb_k<2>, dim3(1024), dim3(256), 0, stream, Op, mlb, out);
}

// Round 10
// 137.204 us; speedup vs baseline: 1.2037x; 1.0312x over previous
//
#include <hip/hip_runtime.h>
#include <hip/hip_bf16.h>

#define B_ 8
#define T_ 2048
#define C_ 1024
#define H_ 64

typedef __bf16 bf16x8 __attribute__((ext_vector_type(8)));
typedef float f32x4 __attribute__((ext_vector_type(4)));

typedef __attribute__((address_space(3))) unsigned int lds_u32;
typedef const __attribute__((address_space(1))) unsigned int glb_u32;
__device__ __forceinline__ void gl_lds16(const void* gp, void* lp) {
  __builtin_amdgcn_global_load_lds((glb_u32*)gp, (lds_u32*)lp, 16, 0, 0);
}

// ---------------- Kernel 0: weight transpose + bf16 cast, STAGED layout ----------------
// Wt2[kb][g][col][8] (bf16) = W_m[c][h] * sc,  c = kb*32+g*8+j, col = m*64+h.
__global__ __launch_bounds__(256) void prep_w_k(const float* __restrict__ Wq,
                                                const float* __restrict__ Wk,
                                                const float* __restrict__ Wv,
                                                __bf16* __restrict__ Wt2) {
  int idx = blockIdx.x * 256 + threadIdx.x;  // 49152 total (3*64*256)
  int m = idx >> 14;
  int rem = idx & 16383;
  int h = rem >> 8;
  int cb = (rem & 255) * 4;   // 4 consecutive c, within one 8-block
  const float* W = (m == 0) ? Wq : ((m == 1) ? Wk : Wv);
  float sc = (m == 0) ? 0.03125f : 1.0f;
  const int col = m * 64 + h;
  const int t = cb >> 5;
  const int g = (cb >> 3) & 3;
  const int j = cb & 7;       // 0 or 4
  __bf16* dst = Wt2 + (((size_t)(t * 4 + g) * 192 + col) * 8 + j);
#pragma unroll
  for (int i = 0; i < 4; ++i) dst[i] = (__bf16)(W[(size_t)(cb + i) * H_ + h] * sc);
}

// ---------------- Kernel 1: QKV projection, 64-row blocks, BK=64, ring-3 ----------------
// grid 256 x 512 thr (8 waves): wave (wr=w>>2, wc=w&3) -> 32 rows x 48 cols.
// Buffer (40 KB): A = 2 x [64 rows][128B] (XOR-swz 16B chunks) = 16 KB;
//                 B = 2 x [4 g][192 col][16B] = 24 KB.  Ring-3 = 120 KB LDS.
__global__ __launch_bounds__(512) void qkv_k(const float* __restrict__ x,
                                             const __bf16* __restrict__ Wt2,
                                             __bf16* __restrict__ q,
                                             __bf16* __restrict__ kk,
                                             __bf16* __restrict__ vt) {
  __shared__ __align__(16) char smem[122880];
  const int tid = threadIdx.x;
  const int lane = tid & 63;
  const int w = tid >> 6;      // 0..7
  const int wr = w >> 2;       // row half
  const int wc = w & 3;        // col quarter
  const int l15 = lane & 15;
  const int g = lane >> 4;
  const int row0 = blockIdx.x * 64;

  // staging addresses (per thread: 2 A-chunks + 3 B-chunks = 5 gl_lds/step)
  const int srow = tid >> 3;                   // 0..63
  const int sch = (tid & 7) ^ (srow & 7);      // source pre-swizzle (A)
  const char* agsrc = (const char*)x + ((size_t)(row0 + srow) * C_ + 0) * 4 + sch * 16;
  const int adst = tid * 16;
  const char* b2src = (const char*)Wt2 + tid * 16;
  const int bdst = 16384 + tid * 16;

  f32x4 acc[2][3];
#pragma unroll
  for (int rt = 0; rt < 2; ++rt)
#pragma unroll
    for (int ctl = 0; ctl < 3; ++ctl) acc[rt][ctl] = (f32x4)0.0f;

  auto stage = [&](int s, int bufo) {
    const char* as = agsrc + (size_t)s * 256;
    gl_lds16(as, smem + bufo + adst);
    gl_lds16(as + 128, smem + bufo + 8192 + adst);
    const char* bs = b2src + (size_t)s * 24576;
    gl_lds16(bs, smem + bufo + bdst);
    gl_lds16(bs + 8192, smem + bufo + 8192 + bdst);
    gl_lds16(bs + 16384, smem + bufo + 16384 + bdst);
  };

  // prologue: stage s=0,1
  stage(0, 0);
  stage(1, 40960);

  for (int s = 0; s < 16; ++s) {
    if (s < 15) {
      asm volatile("s_waitcnt vmcnt(5)" ::: "memory");
    } else {
      asm volatile("s_waitcnt vmcnt(0)" ::: "memory");
    }
    __builtin_amdgcn_s_barrier();
    if (s + 2 < 16) stage(s + 2, ((s + 2) % 3) * 40960);
    const int bufo = (s % 3) * 40960;
#pragma unroll
    for (int kbr = 0; kbr < 2; ++kbr) {
      const char* A = smem + bufo + kbr * 8192;
      const char* Bq = smem + bufo + 16384 + kbr * 12288 + g * 3072;
      bf16x8 af[2];
#pragma unroll
      for (int rt = 0; rt < 2; ++rt) {
        const int row = wr * 32 + rt * 16 + l15;
        const char* ab = A + row * 128;
        f32x4 a0 = *(const f32x4*)(ab + ((((g << 1)) ^ (row & 7)) << 4));
        f32x4 a1 = *(const f32x4*)(ab + ((((g << 1) | 1) ^ (row & 7)) << 4));
#pragma unroll
        for (int j = 0; j < 4; ++j) {
          af[rt][j] = (__bf16)a0[j];
          af[rt][4 + j] = (__bf16)a1[j];
        }
      }
#pragma unroll
      for (int ctl = 0; ctl < 3; ++ctl) {
        const int col = wc * 48 + ctl * 16 + l15;
        bf16x8 bf = *(const bf16x8*)(Bq + col * 16);
        acc[0][ctl] = __builtin_amdgcn_mfma_f32_16x16x32_bf16(af[0], bf, acc[0][ctl], 0, 0, 0);
        acc[1][ctl] = __builtin_amdgcn_mfma_f32_16x16x32_bf16(af[1], bf, acc[1][ctl], 0, 0, 0);
      }
    }
  }

  __syncthreads();  // compute(15) read buf0; V-tile below reuses smem[0,8192)

  // epilogue: q/k direct, v via swizzled LDS transpose -> vt[b][h][t]
#pragma unroll
  for (int rt = 0; rt < 2; ++rt)
#pragma unroll
    for (int ctl = 0; ctl < 3; ++ctl) {
      const int cb = wc * 48 + ctl * 16;
      const int m = cb >> 6;
      const int drow = row0 + wr * 32 + rt * 16 + g * 4;
      if (m == 0) {
#pragma unroll
        for (int r = 0; r < 4; ++r)
          q[(size_t)(drow + r) * H_ + (cb & 63) + l15] = (__bf16)acc[rt][ctl][r];
      } else if (m == 1) {
#pragma unroll
        for (int r = 0; r < 4; ++r)
          kk[(size_t)(drow + r) * H_ + (cb & 63) + l15] = (__bf16)acc[rt][ctl][r];
      } else {
        const int vh = (cb - 128) + l15;
        const int tl = wr * 32 + rt * 16 + g * 4;   // t-local 0..63
        union { ushort4 u; __bf16 h[4]; } pk;
#pragma unroll
        for (int r = 0; r < 4; ++r) pk.h[r] = (__bf16)acc[rt][ctl][r];
        int off = ((vh * 64 + tl) * 2) ^ ((vh & 7) << 4);
        *(ushort4*)(smem + off) = pk.u;
      }
    }
  __syncthreads();
  {
    const int h = tid >> 3;          // 0..63
    const int t8 = (tid & 7) * 8;    // 0..56
    const int sw = (h & 7) << 4;
    union { uint4 u; char c[16]; } v;
    v.u = *(const uint4*)(smem + (((h * 64 + t8) * 2) ^ sw));
    const int bb = blockIdx.x >> 5;
    const int tglob = (blockIdx.x & 31) * 64 + t8;
    *(uint4*)(vt + ((size_t)bb * 64 + h) * T_ + tglob) = v.u;
  }
}

// ---------------- Kernel 2: causal flash attention, split-KV=2, BALANCED mapping ----------------
// 512 blocks; bid<256: (b=i&7, qb=t, p=0); bid>=256: (b=i&7, qb=31-t, p=1), t=i>>3.
// Paired blocks (i, i+256) land on the same CU (round-robin) with complementary
// iteration counts ceil((t+1)/2)+floor((32-t)/2) = 16..17 -> flat CU load.
// b = bid&7 also gives each XCD exclusive batch affinity (K/V/vt L2-resident).
// LDS: ring4 x {K 8KB + V 8KB} = 64 KB + P 8 KB = 72 KB -> 2 blocks/CU
__global__ __launch_bounds__(256) void attn_k(const __bf16* __restrict__ q,
                                              const __bf16* __restrict__ k,
                                              const __bf16* __restrict__ vt,
                                              float* __restrict__ Opart,
                                              float2* __restrict__ ml) {
  __shared__ __align__(16) char smem[73728];
  const int bid = blockIdx.x;
  const int half = bid >> 8;           // piece index p
  const int i0 = bid & 255;
  const int b = i0 & 7;
  const int t0q = i0 >> 3;             // 0..31
  const int qb = half ? (31 - t0q) : t0q;
  const int p = half;
  const int tid = threadIdx.x;
  const int lane = tid & 63;
  const int w = tid >> 6;
  const int l15 = lane & 15;
  const int g = lane >> 4;
  const size_t qkbase = (size_t)b * T_ * H_;
  const int qr0 = qb * 64 + w * 16;

  const __bf16* qp = q + qkbase + (size_t)(qr0 + l15) * H_ + g * 8;
  bf16x8 aq0 = *(const bf16x8*)qp;
  bf16x8 aq1 = *(const bf16x8*)(qp + 32);
  // drain Q loads so in-loop vmcnt counting is exact
  asm volatile("s_waitcnt vmcnt(0)" ::: "memory");

  // staging: K tile 64x128B (row=kv, chunk=h/8), V tile 64x128B (row=h, chunk=t/8)
  const int r0c = tid >> 3, x0c = (tid & 7) ^ (r0c & 7);
  const int r1c = (tid + 256) >> 3, x1c = (tid & 7) ^ (r1c & 7);
  const __bf16* ks0 = k + qkbase + (size_t)r0c * H_ + x0c * 8;
  const __bf16* ks1 = k + qkbase + (size_t)r1c * H_ + x1c * 8;
  const __bf16* vbase = vt + (size_t)b * 64 * T_;
  const __bf16* vs0 = vbase + (size_t)r0c * T_ + x0c * 8;
  const __bf16* vs1 = vbase + (size_t)r1c * T_ + x1c * 8;
  const int d0 = tid * 16, d1 = 4096 + tid * 16;

  auto stage = [&](int kvb, int bufo) {
    gl_lds16(ks0 + (size_t)kvb * H_, smem + bufo + d0);
    gl_lds16(ks1 + (size_t)kvb * H_, smem + bufo + d1);
    gl_lds16(vs0 + kvb, smem + bufo + 8192 + d0);
    gl_lds16(vs1 + kvb, smem + bufo + 8192 + d1);
  };

  f32x4 accO[4];
#pragma unroll
  for (int i = 0; i < 4; ++i) accO[i] = (f32x4)0.0f;
  float mrow[4] = {-1e30f, -1e30f, -1e30f, -1e30f};
  float lsum[4] = {0.f, 0.f, 0.f, 0.f};
  char* pb = smem + 65536 + w * 2048;

  const int len = (qb + 2) >> 1;  // ceil((qb+1)/2)
  const int kb0 = p * len;
  int kbend = kb0 + len;
  if (kbend > qb + 1) kbend = qb + 1;
  const int n = kbend - kb0;

  if (n > 0) {
    stage(kb0 * 64, 0);
    if (n > 1) stage((kb0 + 1) * 64, 16384);
    if (n > 2) stage((kb0 + 2) * 64, 32768);
    for (int i = 0; i < n; ++i) {
      const int remn = n - 1 - i;
      if (remn >= 2) {
        asm volatile("s_waitcnt vmcnt(8)" ::: "memory");
      } else if (remn == 1) {
        asm volatile("s_waitcnt vmcnt(4)" ::: "memory");
      } else {
        asm volatile("s_waitcnt vmcnt(0)" ::: "memory");
      }
      __builtin_amdgcn_s_barrier();
      if (i + 3 < n) stage((kb0 + i + 3) * 64, ((i + 3) & 3) << 14);
      const int kb = kb0 + i;
      const int kvb = kb * 64;
      const char* kbuf = smem + ((i & 3) << 14);
      const char* vbuf = kbuf + 8192;
      // S = Q K^T (scale pre-folded into q)
      f32x4 s[4];
#pragma unroll
      for (int ct = 0; ct < 4; ++ct) {
        const int row = ct * 16 + l15;
        bf16x8 b0 = *(const bf16x8*)(kbuf + row * 128 + ((g ^ (row & 7)) << 4));
        bf16x8 b1 = *(const bf16x8*)(kbuf + row * 128 + (((g + 4) ^ (row & 7)) << 4));
        f32x4 z = (f32x4)0.0f;
        z = __builtin_amdgcn_mfma_f32_16x16x32_bf16(aq0, b0, z, 0, 0, 0);
        z = __builtin_amdgcn_mfma_f32_16x16x32_bf16(aq1, b1, z, 0, 0, 0);
        s[ct] = z;
      }
      if (kb == qb) {  // causal mask on diagonal block
#pragma unroll
        for (int ct = 0; ct < 4; ++ct)
#pragma unroll
          for (int r = 0; r < 4; ++r)
            if (kvb + ct * 16 + l15 > qr0 + g * 4 + r) s[ct][r] = -1e30f;
      }
      // wave-parallel online softmax
      float al[4];
#pragma unroll
      for (int r = 0; r < 4; ++r) {
        float v = fmaxf(fmaxf(s[0][r], s[1][r]), fmaxf(s[2][r], s[3][r]));
        v = fmaxf(v, __shfl_xor(v, 1, 64));
        v = fmaxf(v, __shfl_xor(v, 2, 64));
        v = fmaxf(v, __shfl_xor(v, 4, 64));
        v = fmaxf(v, __shfl_xor(v, 8, 64));
        float m2 = fmaxf(mrow[r], v);
        al[r] = __expf(mrow[r] - m2);
        mrow[r] = m2;
      }
#pragma unroll
      for (int ct = 0; ct < 4; ++ct)
#pragma unroll
        for (int r = 0; r < 4; ++r) s[ct][r] = __expf(s[ct][r] - mrow[r]);
#pragma unroll
      for (int r = 0; r < 4; ++r) {
        lsum[r] = lsum[r] * al[r] + (s[0][r] + s[1][r]) + (s[2][r] + s[3][r]);
#pragma unroll
        for (int hct = 0; hct < 4; ++hct) accO[hct][r] *= al[r];
      }
      // P -> per-wave LDS tile (swizzled), read back as A-fragments
#pragma unroll
      for (int ct = 0; ct < 4; ++ct)
#pragma unroll
        for (int r = 0; r < 4; ++r) {
          int qrow = g * 4 + r;
          int off = ((qrow * 64 + ct * 16 + l15) * 2) ^ ((qrow & 7) << 4);
          *(__bf16*)(pb + off) = (__bf16)s[ct][r];
        }
#pragma unroll
      for (int ks = 0; ks < 2; ++ks) {
        int off = ((l15 * 64 + ks * 32 + g * 8) * 2) ^ ((l15 & 7) << 4);
        bf16x8 pa = *(const bf16x8*)(pb + off);
#pragma unroll
        for (int hct = 0; hct < 4; ++hct) {
          const int h = hct * 16 + l15;
          const int chunk = ks * 4 + g;
          bf16x8 bv = *(const bf16x8*)(vbuf + h * 128 + ((chunk ^ (h & 7)) << 4));
          accO[hct] = __builtin_amdgcn_mfma_f32_16x16x32_bf16(pa, bv, accO[hct], 0, 0, 0);
        }
      }
    }
  }
  // reduce lsum across 16-lane group; write partials (unnormalized)
#pragma unroll
  for (int r = 0; r < 4; ++r) {
    float v = lsum[r];
    v += __shfl_xor(v, 1, 64);
    v += __shfl_xor(v, 2, 64);
    v += __shfl_xor(v, 4, 64);
    v += __shfl_xor(v, 8, 64);
    lsum[r] = v;
  }
  float* op = Opart + ((size_t)p * (B_ * T_) + (size_t)b * T_ + qr0) * H_;
#pragma unroll
  for (int hct = 0; hct < 4; ++hct)
#pragma unroll
    for (int r = 0; r < 4; ++r)
      op[(size_t)(g * 4 + r) * H_ + hct * 16 + l15] = accO[hct][r];
  if (l15 == 0) {
#pragma unroll
    for (int r = 0; r < 4; ++r)
      ml[(size_t)p * (B_ * T_) + (size_t)b * T_ + qr0 + g * 4 + r] =
          make_float2(mrow[r], lsum[r]);
  }
}

// ---------------- Kernel 3: combine split-KV partials ----------------
template <int SPLIT>
__global__ __launch_bounds__(256) void comb_k(const float* __restrict__ Opart,
                                              const float2* __restrict__ ml,
                                              float* __restrict__ out) {
  int gid = blockIdx.x * 256 + threadIdx.x;  // 262144 = 16384 rows x 16
  int row = gid >> 4;
  int h4 = (gid & 15) * 4;
  float m[SPLIT], l[SPLIT];
#pragma unroll
  for (int p = 0; p < SPLIT; ++p) {
    float2 t = ml[(size_t)p * (B_ * T_) + row];
    m[p] = t.x;
    l[p] = t.y;
  }
  float M = -1e30f;
#pragma unroll
  for (int p = 0; p < SPLIT; ++p) M = fmaxf(M, m[p]);
  float wp[SPLIT], wsum = 0.f;
#pragma unroll
  for (int p = 0; p < SPLIT; ++p) {
    wp[p] = __expf(m[p] - M);
    wsum += wp[p] * l[p];
  }
  float4 o = make_float4(0.f, 0.f, 0.f, 0.f);
#pragma unroll
  for (int p = 0; p < SPLIT; ++p) {
    float4 a = *(const float4*)(Opart + ((size_t)p * (B_ * T_) + row) * H_ + h4);
    o.x += wp[p] * a.x;
    o.y += wp[p] * a.y;
    o.z += wp[p] * a.z;
    o.w += wp[p] * a.w;
  }
  float inv = 1.0f / wsum;
  *(float4*)(out + (size_t)row * H_ + h4) =
      make_float4(o.x * inv, o.y * inv, o.z * inv, o.w * inv);
}

// ---------------- launcher ----------------
extern "C" void kernel_launch(void* const* d_in, const int* in_sizes, int n_in,
                              void* d_out, int out_size, void* d_ws, size_t ws_size,
                              hipStream_t stream) {
  const float* x  = (const float*)d_in[0];
  const float* Wq = (const float*)d_in[1];
  const float* Wk = (const float*)d_in[2];
  const float* Wv = (const float*)d_in[3];
  float* out = (float*)d_out;
  char* ws = (char*)d_ws;
  __bf16* Wt2  = (__bf16*)ws;                  // 384 KiB (staged layout)
  __bf16* qb   = (__bf16*)(ws + 0x60000);      // 2 MiB
  __bf16* kb   = (__bf16*)(ws + 0x260000);     // 2 MiB
  __bf16* vtb  = (__bf16*)(ws + 0x460000);     // 2 MiB (vt[b][h][t])
  float*  Op   = (float*)(ws + 0x660000);      // 8 MiB (2 x 16384 x 64 f32)
  float2* mlb  = (float2*)(ws + 0xE60000);     // 256 KiB

  hipLaunchKernelGGL(prep_w_k, dim3(192), dim3(256), 0, stream, Wq, Wk, Wv, Wt2);
  hipLaunchKernelGGL(qkv_k, dim3(256), dim3(512), 0, stream, x, Wt2, qb, kb, vtb);
  hipLaunchKernelGGL(attn_k, dim3(512), dim3(256), 0, stream, qb, kb, vtb, Op, mlb);
  hipLaunchKernelGGL(comb_k<2>, dim3(1024), dim3(256), 0, stream, Op, mlb, out);
}